// Round 10
// baseline (268.967 us; speedup 1.0000x reference)
//
#include <hip/hip_runtime.h>
#include <math.h>

#define DIM    768
#define HEADS  12
#define HIDDEN 3072
#define SEQ    1024
#define NTOK   8192
#define QKVLD  2304

typedef __bf16 bf16_t;
typedef __bf16 bf16x4 __attribute__((ext_vector_type(4)));
typedef __bf16 bf16x8 __attribute__((ext_vector_type(8)));
typedef float  f32x4  __attribute__((ext_vector_type(4)));

union ABFrag { bf16x4 h[2]; bf16x8 v; };

__device__ __forceinline__ void gload16(const void* g, void* l) {
  __builtin_amdgcn_global_load_lds(
      (const __attribute__((address_space(1))) void*)g,
      (__attribute__((address_space(3))) void*)l, 16, 0, 0);
}

__device__ __forceinline__ f32x4 mfma16(bf16x8 a, bf16x8 b, f32x4 c) {
  return __builtin_amdgcn_mfma_f32_16x16x32_bf16(a, b, c, 0, 0, 0);
}

// split k-map frag load (attn Q only): k = 4g + j%4 + 16*(j/4), both operands.
__device__ __forceinline__ ABFrag load_frag(const bf16_t* rowp, int g) {
  ABFrag f;
  f.h[0] = *(const bf16x4*)(rowp + 4 * g);
  f.h[1] = *(const bf16x4*)(rowp + 4 * g + 16);
  return f;
}

// BK=64 GEMM frag load: [rows][64] tile (128B rows), chunk lc stored at lc^(row&7).
__device__ __forceinline__ bf16x8 ldsfrag(const bf16_t* base, int row, int lc) {
  return *(const bf16x8*)(base + row * 64 + ((lc ^ (row & 7)) << 3));
}

// BK=32 GEMM frag load: [rows][32] tile (64B rows) — naturally bank-staggered
// (row*64B = 16 banks offset per row), linear layout, no swizzle needed.
__device__ __forceinline__ bf16x8 ldsfrag32(const bf16_t* base, int row, int g) {
  return *(const bf16x8*)(base + row * 32 + g * 8);
}

// tanh-form GELU: 0.5x(1+tanh(sqrt(2/pi)(x+0.044715x^3))), max err vs exact ~3e-3.
__device__ __forceinline__ float gelu_f(float v) {
  float u = v * fmaf(v * v, 0.0356774081f, 0.7978845608f);
  u = fminf(u, 15.0f);
  float t = __builtin_amdgcn_exp2f(u * 2.8853900817779268f);  // e^{2u}
  return v * t * __builtin_amdgcn_rcpf(t + 1.0f);
}

// ---------------- LayerNorm: wave-per-row, fp32 in -> bf16 out ----------------
__global__ __launch_bounds__(256) void ln_kernel(
    const float* __restrict__ x, const float* __restrict__ gw,
    const float* __restrict__ bw, bf16_t* __restrict__ out) {
  const int row = blockIdx.x * 4 + (threadIdx.x >> 6);
  const int lane = threadIdx.x & 63;
  const float* xr = x + (size_t)row * DIM;
  f32x4 v[3];
  float s = 0.f, s2 = 0.f;
  #pragma unroll
  for (int i = 0; i < 3; ++i) {
    v[i] = *(const f32x4*)(xr + lane * 4 + i * 256);
    #pragma unroll
    for (int j = 0; j < 4; ++j) { s += v[i][j]; s2 += v[i][j] * v[i][j]; }
  }
  #pragma unroll
  for (int o = 32; o > 0; o >>= 1) {
    s += __shfl_xor(s, o);
    s2 += __shfl_xor(s2, o);
  }
  const float mu  = s * (1.0f / DIM);
  const float var = s2 * (1.0f / DIM) - mu * mu;
  const float rs  = rsqrtf(var + 1e-5f);
  bf16_t* orow = out + (size_t)row * DIM;
  #pragma unroll
  for (int i = 0; i < 3; ++i) {
    const int c = lane * 4 + i * 256;
    f32x4 gv = *(const f32x4*)(gw + c);
    f32x4 bv = *(const f32x4*)(bw + c);
    bf16x4 o4;
    #pragma unroll
    for (int j = 0; j < 4; ++j)
      o4[j] = (bf16_t)((v[i][j] - mu) * rs * gv[j] + bv[j]);
    *(bf16x4*)(orow + c) = o4;
  }
}

// ------------- Weight transpose+convert: W[K][N] f32 -> Wt[N][K] bf16 -------------
__global__ __launch_bounds__(256) void wtrans_kernel(
    const float* __restrict__ W, bf16_t* __restrict__ Wt, int K, int N) {
  __shared__ float tile[32][33];
  const int tx = threadIdx.x, ty = threadIdx.y;
  const int n0 = blockIdx.x * 32, k0 = blockIdx.y * 32;
  #pragma unroll
  for (int i = 0; i < 4; ++i)
    tile[ty + i * 8][tx] = W[(size_t)(k0 + ty + i * 8) * N + n0 + tx];
  __syncthreads();
  #pragma unroll
  for (int i = 0; i < 4; ++i)
    Wt[(size_t)(n0 + ty + i * 8) * K + k0 + tx] = (bf16_t)tile[tx][ty + i * 8];
}

// ------------- V transpose per head: qkv bf16 -> Vt[bh][64][SEQ] bf16 -------------
__global__ __launch_bounds__(256) void vtrans_kernel(
    const bf16_t* __restrict__ qkv, bf16_t* __restrict__ vt) {
  __shared__ bf16_t tile[64][65];
  const int bh = blockIdx.y, b = bh / HEADS, h = bh % HEADS;
  const int n0 = blockIdx.x * 64;
  const int t = threadIdx.x;
  const int c = t & 63, rr = t >> 6;
  const bf16_t* src = qkv + (size_t)(b * SEQ + n0) * QKVLD + 2 * DIM + h * 64;
  #pragma unroll
  for (int i = 0; i < 16; ++i)
    tile[c][rr + i * 4] = src[(size_t)(rr + i * 4) * QKVLD + c];
  __syncthreads();
  bf16_t* dst = vt + (size_t)bh * 64 * SEQ + n0;
  #pragma unroll
  for (int i = 0; i < 16; ++i)
    dst[(size_t)(rr + i * 4) * SEQ + c] = tile[rr + i * 4][c];
}

// ---- Double-buffered BK=32 GEMM (occupancy + pipeline): BM=BN=128, 32 KB LDS ----
// One __syncthreads per K-step; next tile's loads issued right after the sync so
// HBM latency hides under the current tile's ds_read+MFMA, at 5 blocks/CU.
template <int MODE>
__global__ __launch_bounds__(256) void gemm_db32(
    const bf16_t* __restrict__ A, const bf16_t* __restrict__ Bt,
    int N, int K,
    const float* __restrict__ bias, const float* __restrict__ res,
    void* __restrict__ outv, int gx) {
  __shared__ bf16_t sA[2][128 * 32];
  __shared__ bf16_t sB[2][128 * 32];
  const int tid = threadIdx.x;
  const int lane = tid & 63;
  const int wid = tid >> 6;
  const int g = lane >> 4, r16 = lane & 15;

  const int nwg = gridDim.x;
  const int cpx = nwg >> 3;
  const int sw = (blockIdx.x & 7) * cpx + (blockIdx.x >> 3);
  const int bx = sw % gx, by = sw / gx;
  const int row0 = by * 128, col0 = bx * 128;
  const int wr = (wid >> 1) * 64, wc = (wid & 1) * 64;

  // staging: chunk c = rnd*256+tid -> row c>>2, kpart c&3 (linear, no swizzle)
  auto stage = [&](int p, int kt) {
    #pragma unroll
    for (int rnd = 0; rnd < 2; ++rnd) {
      const int c = rnd * 256 + tid;
      gload16(A + (size_t)(row0 + (c >> 2)) * K + (size_t)kt * 32 + (c & 3) * 8,
              &sA[p][c * 8]);
    }
    #pragma unroll
    for (int rnd = 0; rnd < 2; ++rnd) {
      const int c = rnd * 256 + tid;
      gload16(Bt + (size_t)(col0 + (c >> 2)) * K + (size_t)kt * 32 + (c & 3) * 8,
              &sB[p][c * 8]);
    }
  };

  f32x4 acc[4][4];
  #pragma unroll
  for (int m = 0; m < 4; ++m)
    #pragma unroll
    for (int n = 0; n < 4; ++n) acc[m][n] = f32x4{0.f, 0.f, 0.f, 0.f};

  const int kSteps = K >> 5;
  stage(0, 0);
  for (int kt = 0; kt < kSteps; ++kt) {
    const int cur = kt & 1;
    __syncthreads();  // drains stage(cur) issued last iter + prev ds_reads
    if (kt + 1 < kSteps) stage(cur ^ 1, kt + 1);

    bf16x8 af[4], bfr[4];
    #pragma unroll
    for (int m = 0; m < 4; ++m) af[m] = ldsfrag32(&sA[cur][0], wr + m * 16 + r16, g);
    #pragma unroll
    for (int n = 0; n < 4; ++n) bfr[n] = ldsfrag32(&sB[cur][0], wc + n * 16 + r16, g);
    #pragma unroll
    for (int m = 0; m < 4; ++m)
      #pragma unroll
      for (int n = 0; n < 4; ++n)
        acc[m][n] = mfma16(af[m], bfr[n], acc[m][n]);
  }

  // Epilogue. C/D layout (HW-verified): col = lane&15, row = 4*(lane>>4)+reg.
  #pragma unroll
  for (int m = 0; m < 4; ++m) {
    const int rowb = row0 + wr + m * 16 + 4 * g;
    #pragma unroll
    for (int n = 0; n < 4; ++n) {
      const int col = col0 + wc + n * 16 + r16;
      const float bv = bias[col];
      #pragma unroll
      for (int r = 0; r < 4; ++r) {
        const size_t idx = (size_t)(rowb + r) * N + col;
        float v = acc[m][n][r] + bv;
        if (MODE == 0) {
          ((bf16_t*)outv)[idx] = (bf16_t)v;
        } else if (MODE == 1) {
          ((float*)outv)[idx] = v + res[idx];
        } else {
          ((bf16_t*)outv)[idx] = (bf16_t)gelu_f(v);
        }
      }
    }
  }
}

// ---- Double-buffered BK=64 GEMM (latency regime, grid-limited ~1.5 blocks/CU) ----
template <int MODE>
__global__ __launch_bounds__(256) void gemm_db(
    const bf16_t* __restrict__ A, const bf16_t* __restrict__ Bt,
    int N, int K,
    const float* __restrict__ bias, const float* __restrict__ res,
    void* __restrict__ outv, int gx) {
  __shared__ bf16_t sA[2][128 * 64];
  __shared__ bf16_t sB[2][128 * 64];
  const int tid = threadIdx.x;
  const int lane = tid & 63;
  const int wid = tid >> 6;
  const int g = lane >> 4, r16 = lane & 15;

  const int nwg = gridDim.x;
  const int cpx = nwg >> 3;
  const int sw = (blockIdx.x & 7) * cpx + (blockIdx.x >> 3);
  const int bx = sw % gx, by = sw / gx;
  const int row0 = by * 128, col0 = bx * 128;
  const int wr = (wid >> 1) * 64, wc = (wid & 1) * 64;

  auto stage = [&](int p, int kt) {
    #pragma unroll
    for (int rnd = 0; rnd < 4; ++rnd) {
      const int c = rnd * 256 + tid;
      const int row = c >> 3, scp = (c & 7) ^ (row & 7);
      gload16(A + (size_t)(row0 + row) * K + (size_t)kt * 64 + scp * 8,
              &sA[p][c * 8]);
    }
    #pragma unroll
    for (int rnd = 0; rnd < 4; ++rnd) {
      const int c = rnd * 256 + tid;
      const int row = c >> 3, scp = (c & 7) ^ (row & 7);
      gload16(Bt + (size_t)(col0 + row) * K + (size_t)kt * 64 + scp * 8,
              &sB[p][c * 8]);
    }
  };

  f32x4 acc[4][4];
  #pragma unroll
  for (int m = 0; m < 4; ++m)
    #pragma unroll
    for (int n = 0; n < 4; ++n) acc[m][n] = f32x4{0.f, 0.f, 0.f, 0.f};

  const int kSteps = K >> 6;
  stage(0, 0);
  for (int kt = 0; kt < kSteps; ++kt) {
    const int cur = kt & 1;
    __syncthreads();
    if (kt + 1 < kSteps) stage(cur ^ 1, kt + 1);

    bf16x8 af[4][2], bfr[4][2];
    #pragma unroll
    for (int m = 0; m < 4; ++m)
      #pragma unroll
      for (int kk = 0; kk < 2; ++kk)
        af[m][kk] = ldsfrag(&sA[cur][0], wr + m * 16 + r16, kk * 4 + g);
    #pragma unroll
    for (int n = 0; n < 4; ++n)
      #pragma unroll
      for (int kk = 0; kk < 2; ++kk)
        bfr[n][kk] = ldsfrag(&sB[cur][0], wc + n * 16 + r16, kk * 4 + g);
    #pragma unroll
    for (int kk = 0; kk < 2; ++kk)
      #pragma unroll
      for (int m = 0; m < 4; ++m)
        #pragma unroll
        for (int n = 0; n < 4; ++n)
          acc[m][n] = mfma16(af[m][kk], bfr[n][kk], acc[m][n]);
  }

  #pragma unroll
  for (int m = 0; m < 4; ++m) {
    const int rowb = row0 + wr + m * 16 + 4 * g;
    #pragma unroll
    for (int n = 0; n < 4; ++n) {
      const int col = col0 + wc + n * 16 + r16;
      const float bv = bias[col];
      #pragma unroll
      for (int r = 0; r < 4; ++r) {
        const size_t idx = (size_t)(rowb + r) * N + col;
        float v = acc[m][n][r] + bv;
        if (MODE == 0) {
          ((bf16_t*)outv)[idx] = (bf16_t)v;
        } else if (MODE == 1) {
          ((float*)outv)[idx] = v + res[idx];
        } else {
          ((bf16_t*)outv)[idx] = (bf16_t)gelu_f(v);
        }
      }
    }
  }
}

// ---- Flash attention: QBLK=128 (8 waves), KVBLK=64, fixed-shift exp2 softmax ----
// Grid (x=bh, y=qtile): XCD = bh%8 -> all q-blocks of one (b,h) share an XCD.
__global__ __launch_bounds__(512) void attn_kernel(
    const bf16_t* __restrict__ qkv, const bf16_t* __restrict__ vt,
    bf16_t* __restrict__ o) {
  __shared__ bf16_t kbuf[2][64 * 64];
  __shared__ bf16_t vbuf[2][64 * 64];
  const int bh = blockIdx.x, b = bh / HEADS, h = bh % HEADS;
  const int q0 = blockIdx.y * 128;
  const int tid = threadIdx.x, lane = tid & 63, wid = tid >> 6;
  const int g = lane >> 4, r16 = lane & 15;

  const bf16_t* qptr = qkv + (size_t)b * SEQ * QKVLD + h * 64;
  const bf16_t* kptr = qptr + DIM;
  const bf16_t* vtp  = vt + (size_t)bh * 64 * SEQ;

  ABFrag aq[2];
  {
    const bf16_t* qr = qptr + (size_t)(q0 + wid * 16 + r16) * QKVLD;
    aq[0] = load_frag(qr, g);
    aq[1] = load_frag(qr + 32, g);
  }

  int off[4][2][2];
  #pragma unroll
  for (int i = 0; i < 4; ++i) {
    const int row = i * 16 + r16, s = row & 7, rp = row * 64;
    #pragma unroll
    for (int e2 = 0; e2 < 2; ++e2) {
      const int o0 = e2 * 32 + 4 * g, o1 = o0 + 16;
      off[i][e2][0] = rp + ((((o0 >> 3) ^ s) << 3) | (o0 & 7));
      off[i][e2][1] = rp + ((((o1 >> 3) ^ s) << 3) | (o1 & 7));
    }
  }

  float lacc = 0.f;
  f32x4 acco[4];
  #pragma unroll
  for (int n = 0; n < 4; ++n) acco[n] = f32x4{0.f, 0.f, 0.f, 0.f};

  const int srow = tid >> 3, sscp = (tid & 7) ^ (srow & 7);
  const bf16_t* kSrc = kptr + (size_t)srow * QKVLD + sscp * 8;
  const bf16_t* vSrc = vtp + (size_t)srow * SEQ + sscp * 8;
  auto stage = [&](int buf, int kv0) {
    gload16(kSrc + (size_t)kv0 * QKVLD, &kbuf[buf][tid * 8]);
    gload16(vSrc + kv0, &vbuf[buf][tid * 8]);
  };

  const float C2 = 0.125f * 1.4426950408889634f;

  stage(0, 0);
  for (int it = 0; it < SEQ / 64; ++it) {
    const int cur = it & 1;
    __syncthreads();
    if (it + 1 < SEQ / 64) stage(cur ^ 1, (it + 1) * 64);
    const bf16_t* kb = kbuf[cur];
    const bf16_t* vb = vbuf[cur];

    f32x4 st[4];
    __builtin_amdgcn_s_setprio(1);
    #pragma unroll
    for (int t = 0; t < 4; ++t) {
      st[t] = f32x4{0.f, 0.f, 0.f, 0.f};
      ABFrag ak0, ak1;
      ak0.h[0] = *(const bf16x4*)(kb + off[t][0][0]);
      ak0.h[1] = *(const bf16x4*)(kb + off[t][0][1]);
      st[t] = mfma16(ak0.v, aq[0].v, st[t]);
      ak1.h[0] = *(const bf16x4*)(kb + off[t][1][0]);
      ak1.h[1] = *(const bf16x4*)(kb + off[t][1][1]);
      st[t] = mfma16(ak1.v, aq[1].v, st[t]);
    }
    __builtin_amdgcn_s_setprio(0);

    float p[4][4];
    #pragma unroll
    for (int t = 0; t < 4; ++t)
      #pragma unroll
      for (int r = 0; r < 4; ++r) {
        float e = __builtin_amdgcn_exp2f(fmaf(st[t][r], C2, -16.0f));
        p[t][r] = e;
        lacc += e;
      }

    ABFrag pa0, pa1;
    #pragma unroll
    for (int r = 0; r < 4; ++r) {
      pa0.h[0][r] = (bf16_t)p[0][r];
      pa0.h[1][r] = (bf16_t)p[1][r];
      pa1.h[0][r] = (bf16_t)p[2][r];
      pa1.h[1][r] = (bf16_t)p[3][r];
    }

    __builtin_amdgcn_s_setprio(1);
    #pragma unroll
    for (int n = 0; n < 4; ++n) {
      ABFrag bv0, bv1;
      bv0.h[0] = *(const bf16x4*)(vb + off[n][0][0]);
      bv0.h[1] = *(const bf16x4*)(vb + off[n][0][1]);
      acco[n] = mfma16(pa0.v, bv0.v, acco[n]);
      bv1.h[0] = *(const bf16x4*)(vb + off[n][1][0]);
      bv1.h[1] = *(const bf16x4*)(vb + off[n][1][1]);
      acco[n] = mfma16(pa1.v, bv1.v, acco[n]);
    }
    __builtin_amdgcn_s_setprio(0);
  }

  float lt = lacc;
  lt += __shfl_xor(lt, 16);
  lt += __shfl_xor(lt, 32);
  float linv[4];
  #pragma unroll
  for (int r = 0; r < 4; ++r) linv[r] = 1.0f / __shfl(lt, 4 * g + r);
  bf16_t* op = o + (size_t)(b * SEQ + q0 + wid * 16 + 4 * g) * DIM + h * 64;
  #pragma unroll
  for (int n = 0; n < 4; ++n)
    #pragma unroll
    for (int r = 0; r < 4; ++r)
      op[(size_t)r * DIM + n * 16 + r16] = (bf16_t)(acco[n][r] * linv[r]);
}

extern "C" void kernel_launch(void* const* d_in, const int* in_sizes, int n_in,
                              void* d_out, int out_size, void* d_ws, size_t ws_size,
                              hipStream_t stream) {
  const float* x      = (const float*)d_in[0];
  const float* ln1_g  = (const float*)d_in[1];
  const float* ln1_b  = (const float*)d_in[2];
  const float* qkv_w  = (const float*)d_in[3];
  const float* qkv_b  = (const float*)d_in[4];
  const float* proj_w = (const float*)d_in[5];
  const float* proj_b = (const float*)d_in[6];
  const float* ln2_g  = (const float*)d_in[7];
  const float* ln2_b  = (const float*)d_in[8];
  const float* fc1_w  = (const float*)d_in[9];
  const float* fc1_b  = (const float*)d_in[10];
  const float* fc2_w  = (const float*)d_in[11];
  const float* fc2_b  = (const float*)d_in[12];
  float* out = (float*)d_out;

  char* ws = (char*)d_ws;
  size_t off = 0;
  auto alloc = [&](size_t bytes) -> void* {
    void* p = ws + off;
    off += (bytes + 255) & ~(size_t)255;
    return p;
  };
  bf16_t* wqkvT  = (bf16_t*)alloc((size_t)QKVLD * DIM * 2);
  bf16_t* wprojT = (bf16_t*)alloc((size_t)DIM * DIM * 2);
  bf16_t* wfc1T  = (bf16_t*)alloc((size_t)HIDDEN * DIM * 2);
  bf16_t* wfc2T  = (bf16_t*)alloc((size_t)DIM * HIDDEN * 2);
  bf16_t* buf1   = (bf16_t*)alloc((size_t)NTOK * DIM * 2);     // h1, then obf
  bf16_t* buf2   = (bf16_t*)alloc((size_t)NTOK * HIDDEN * 2);  // qkvbf, then h3
  bf16_t* buf3   = (bf16_t*)alloc((size_t)NTOK * DIM * 2);     // vt, then h2
  float*  x1     = (float*)alloc((size_t)NTOK * DIM * 4);

  bf16_t* h1 = buf1;     bf16_t* obf = buf1;
  bf16_t* qkvbf = buf2;  bf16_t* h3 = buf2;
  bf16_t* vt = buf3;     bf16_t* h2 = buf3;
  (void)in_sizes; (void)n_in; (void)out_size; (void)ws_size;

  dim3 tb(32, 8);
  wtrans_kernel<<<dim3(QKVLD / 32, DIM / 32), tb, 0, stream>>>(qkv_w, wqkvT, DIM, QKVLD);
  wtrans_kernel<<<dim3(DIM / 32, DIM / 32), tb, 0, stream>>>(proj_w, wprojT, DIM, DIM);
  wtrans_kernel<<<dim3(HIDDEN / 32, DIM / 32), tb, 0, stream>>>(fc1_w, wfc1T, DIM, HIDDEN);
  wtrans_kernel<<<dim3(DIM / 32, HIDDEN / 32), tb, 0, stream>>>(fc2_w, wfc2T, HIDDEN, DIM);

  ln_kernel<<<NTOK / 4, 256, 0, stream>>>(x, ln1_g, ln1_b, h1);
  gemm_db32<0><<<(QKVLD / 128) * (NTOK / 128), 256, 0, stream>>>(
      h1, wqkvT, QKVLD, DIM, qkv_b, nullptr, qkvbf, QKVLD / 128);
  vtrans_kernel<<<dim3(SEQ / 64, 8 * HEADS), 256, 0, stream>>>(qkvbf, vt);
  attn_kernel<<<dim3(8 * HEADS, SEQ / 128), 512, 0, stream>>>(qkvbf, vt, obf);
  gemm_db<1><<<(DIM / 128) * (NTOK / 128), 256, 0, stream>>>(
      obf, wprojT, DIM, DIM, proj_b, x, x1, DIM / 128);
  ln_kernel<<<NTOK / 4, 256, 0, stream>>>(x1, ln2_g, ln2_b, h2);
  gemm_db32<2><<<(HIDDEN / 128) * (NTOK / 128), 256, 0, stream>>>(
      h2, wfc1T, HIDDEN, DIM, fc1_b, nullptr, h3, HIDDEN / 128);
  gemm_db<1><<<(DIM / 128) * (NTOK / 128), 256, 0, stream>>>(
      h3, wfc2T, DIM, HIDDEN, fc2_b, x1, out, DIM / 128);
}

// Round 11
// 235.878 us; speedup vs baseline: 1.1403x; 1.1403x over previous
//
#include <hip/hip_runtime.h>
#include <math.h>

#define DIM    768
#define HEADS  12
#define HIDDEN 3072
#define SEQ    1024
#define NTOK   8192
#define QKVLD  2304

typedef __bf16 bf16_t;
typedef __bf16 bf16x4 __attribute__((ext_vector_type(4)));
typedef __bf16 bf16x8 __attribute__((ext_vector_type(8)));
typedef float  f32x4  __attribute__((ext_vector_type(4)));

union ABFrag { bf16x4 h[2]; bf16x8 v; };

__device__ __forceinline__ void gload16(const void* g, void* l) {
  __builtin_amdgcn_global_load_lds(
      (const __attribute__((address_space(1))) void*)g,
      (__attribute__((address_space(3))) void*)l, 16, 0, 0);
}

__device__ __forceinline__ f32x4 mfma16(bf16x8 a, bf16x8 b, f32x4 c) {
  return __builtin_amdgcn_mfma_f32_16x16x32_bf16(a, b, c, 0, 0, 0);
}

// BK=64 GEMM frag load: [rows][64] tile (128B rows), chunk lc stored at lc^(row&7).
__device__ __forceinline__ bf16x8 ldsfrag(const bf16_t* base, int row, int lc) {
  return *(const bf16x8*)(base + row * 64 + ((lc ^ (row & 7)) << 3));
}

// tanh-form GELU: 0.5x(1+tanh(sqrt(2/pi)(x+0.044715x^3))), max err vs exact ~3e-3.
__device__ __forceinline__ float gelu_f(float v) {
  float u = v * fmaf(v * v, 0.0356774081f, 0.7978845608f);
  u = fminf(u, 15.0f);
  float t = __builtin_amdgcn_exp2f(u * 2.8853900817779268f);  // e^{2u}
  return v * t * __builtin_amdgcn_rcpf(t + 1.0f);
}

// ---------------- LayerNorm: wave-per-row, fp32 in -> bf16 out ----------------
__global__ __launch_bounds__(256) void ln_kernel(
    const float* __restrict__ x, const float* __restrict__ gw,
    const float* __restrict__ bw, bf16_t* __restrict__ out) {
  const int row = blockIdx.x * 4 + (threadIdx.x >> 6);
  const int lane = threadIdx.x & 63;
  const float* xr = x + (size_t)row * DIM;
  f32x4 v[3];
  float s = 0.f, s2 = 0.f;
  #pragma unroll
  for (int i = 0; i < 3; ++i) {
    v[i] = *(const f32x4*)(xr + lane * 4 + i * 256);
    #pragma unroll
    for (int j = 0; j < 4; ++j) { s += v[i][j]; s2 += v[i][j] * v[i][j]; }
  }
  #pragma unroll
  for (int o = 32; o > 0; o >>= 1) {
    s += __shfl_xor(s, o);
    s2 += __shfl_xor(s2, o);
  }
  const float mu  = s * (1.0f / DIM);
  const float var = s2 * (1.0f / DIM) - mu * mu;
  const float rs  = rsqrtf(var + 1e-5f);
  bf16_t* orow = out + (size_t)row * DIM;
  #pragma unroll
  for (int i = 0; i < 3; ++i) {
    const int c = lane * 4 + i * 256;
    f32x4 gv = *(const f32x4*)(gw + c);
    f32x4 bv = *(const f32x4*)(bw + c);
    bf16x4 o4;
    #pragma unroll
    for (int j = 0; j < 4; ++j)
      o4[j] = (bf16_t)((v[i][j] - mu) * rs * gv[j] + bv[j]);
    *(bf16x4*)(orow + c) = o4;
  }
}

// ------------- Weight transpose+convert: W[K][N] f32 -> Wt[N][K] bf16 -------------
__global__ __launch_bounds__(256) void wtrans_kernel(
    const float* __restrict__ W, bf16_t* __restrict__ Wt, int K, int N) {
  __shared__ float tile[32][33];
  const int tx = threadIdx.x, ty = threadIdx.y;
  const int n0 = blockIdx.x * 32, k0 = blockIdx.y * 32;
  #pragma unroll
  for (int i = 0; i < 4; ++i)
    tile[ty + i * 8][tx] = W[(size_t)(k0 + ty + i * 8) * N + n0 + tx];
  __syncthreads();
  #pragma unroll
  for (int i = 0; i < 4; ++i)
    Wt[(size_t)(n0 + ty + i * 8) * K + k0 + tx] = (bf16_t)tile[tx][ty + i * 8];
}

// ------------- V transpose per head: qkv bf16 -> Vt[bh][64][SEQ] bf16 -------------
__global__ __launch_bounds__(256) void vtrans_kernel(
    const bf16_t* __restrict__ qkv, bf16_t* __restrict__ vt) {
  __shared__ bf16_t tile[64][65];
  const int bh = blockIdx.y, b = bh / HEADS, h = bh % HEADS;
  const int n0 = blockIdx.x * 64;
  const int t = threadIdx.x;
  const int c = t & 63, rr = t >> 6;
  const bf16_t* src = qkv + (size_t)(b * SEQ + n0) * QKVLD + 2 * DIM + h * 64;
  #pragma unroll
  for (int i = 0; i < 16; ++i)
    tile[c][rr + i * 4] = src[(size_t)(rr + i * 4) * QKVLD + c];
  __syncthreads();
  bf16_t* dst = vt + (size_t)bh * 64 * SEQ + n0;
  #pragma unroll
  for (int i = 0; i < 16; ++i)
    dst[(size_t)(rr + i * 4) * SEQ + c] = tile[rr + i * 4][c];
}

// ---- Single-buffered GEMM (occupancy regime, grid >= ~1000): BM=BN=128, BK=64 ----
// 32 KB LDS -> ~5 blocks/CU; inter-block TLP hides the staging drain (m114).
template <int MODE>
__global__ __launch_bounds__(256) void gemm_sb(
    const bf16_t* __restrict__ A, const bf16_t* __restrict__ Bt,
    int N, int K,
    const float* __restrict__ bias, const float* __restrict__ res,
    void* __restrict__ outv, int gx) {
  __shared__ bf16_t sA[128 * 64];
  __shared__ bf16_t sB[128 * 64];
  const int tid = threadIdx.x;
  const int lane = tid & 63;
  const int wid = tid >> 6;
  const int g = lane >> 4, r16 = lane & 15;

  const int nwg = gridDim.x;
  const int cpx = nwg >> 3;
  const int sw = (blockIdx.x & 7) * cpx + (blockIdx.x >> 3);
  const int bx = sw % gx, by = sw / gx;
  const int row0 = by * 128, col0 = bx * 128;
  const int wr = (wid >> 1) * 64, wc = (wid & 1) * 64;

  f32x4 acc[4][4];
  #pragma unroll
  for (int m = 0; m < 4; ++m)
    #pragma unroll
    for (int n = 0; n < 4; ++n) acc[m][n] = f32x4{0.f, 0.f, 0.f, 0.f};

  const int kSteps = K >> 6;
  for (int kt = 0; kt < kSteps; ++kt) {
    __syncthreads();
    #pragma unroll
    for (int rnd = 0; rnd < 4; ++rnd) {
      const int c = rnd * 256 + tid;
      const int row = c >> 3, scp = (c & 7) ^ (row & 7);
      gload16(A + (size_t)(row0 + row) * K + (size_t)kt * 64 + scp * 8, &sA[c * 8]);
    }
    #pragma unroll
    for (int rnd = 0; rnd < 4; ++rnd) {
      const int c = rnd * 256 + tid;
      const int row = c >> 3, scp = (c & 7) ^ (row & 7);
      gload16(Bt + (size_t)(col0 + row) * K + (size_t)kt * 64 + scp * 8, &sB[c * 8]);
    }
    __syncthreads();
    bf16x8 af[4][2], bfr[4][2];
    #pragma unroll
    for (int m = 0; m < 4; ++m)
      #pragma unroll
      for (int kk = 0; kk < 2; ++kk)
        af[m][kk] = ldsfrag(sA, wr + m * 16 + r16, kk * 4 + g);
    #pragma unroll
    for (int n = 0; n < 4; ++n)
      #pragma unroll
      for (int kk = 0; kk < 2; ++kk)
        bfr[n][kk] = ldsfrag(sB, wc + n * 16 + r16, kk * 4 + g);
    #pragma unroll
    for (int kk = 0; kk < 2; ++kk)
      #pragma unroll
      for (int m = 0; m < 4; ++m)
        #pragma unroll
        for (int n = 0; n < 4; ++n)
          acc[m][n] = mfma16(af[m][kk], bfr[n][kk], acc[m][n]);
  }

  #pragma unroll
  for (int m = 0; m < 4; ++m) {
    const int rowb = row0 + wr + m * 16 + 4 * g;
    #pragma unroll
    for (int n = 0; n < 4; ++n) {
      const int col = col0 + wc + n * 16 + r16;
      const float bv = bias[col];
      #pragma unroll
      for (int r = 0; r < 4; ++r) {
        const size_t idx = (size_t)(rowb + r) * N + col;
        float v = acc[m][n][r] + bv;
        if (MODE == 0) {
          ((bf16_t*)outv)[idx] = (bf16_t)v;
        } else if (MODE == 1) {
          ((float*)outv)[idx] = v + res[idx];
        } else {
          ((bf16_t*)outv)[idx] = (bf16_t)gelu_f(v);
        }
      }
    }
  }
}

// ---- Double-buffered BK=64 GEMM (latency regime, grid-limited ~1.5 blocks/CU) ----
template <int MODE>
__global__ __launch_bounds__(256) void gemm_db(
    const bf16_t* __restrict__ A, const bf16_t* __restrict__ Bt,
    int N, int K,
    const float* __restrict__ bias, const float* __restrict__ res,
    void* __restrict__ outv, int gx) {
  __shared__ bf16_t sA[2][128 * 64];
  __shared__ bf16_t sB[2][128 * 64];
  const int tid = threadIdx.x;
  const int lane = tid & 63;
  const int wid = tid >> 6;
  const int g = lane >> 4, r16 = lane & 15;

  const int nwg = gridDim.x;
  const int cpx = nwg >> 3;
  const int sw = (blockIdx.x & 7) * cpx + (blockIdx.x >> 3);
  const int bx = sw % gx, by = sw / gx;
  const int row0 = by * 128, col0 = bx * 128;
  const int wr = (wid >> 1) * 64, wc = (wid & 1) * 64;

  auto stage = [&](int p, int kt) {
    #pragma unroll
    for (int rnd = 0; rnd < 4; ++rnd) {
      const int c = rnd * 256 + tid;
      const int row = c >> 3, scp = (c & 7) ^ (row & 7);
      gload16(A + (size_t)(row0 + row) * K + (size_t)kt * 64 + scp * 8,
              &sA[p][c * 8]);
    }
    #pragma unroll
    for (int rnd = 0; rnd < 4; ++rnd) {
      const int c = rnd * 256 + tid;
      const int row = c >> 3, scp = (c & 7) ^ (row & 7);
      gload16(Bt + (size_t)(col0 + row) * K + (size_t)kt * 64 + scp * 8,
              &sB[p][c * 8]);
    }
  };

  f32x4 acc[4][4];
  #pragma unroll
  for (int m = 0; m < 4; ++m)
    #pragma unroll
    for (int n = 0; n < 4; ++n) acc[m][n] = f32x4{0.f, 0.f, 0.f, 0.f};

  const int kSteps = K >> 6;
  stage(0, 0);
  for (int kt = 0; kt < kSteps; ++kt) {
    const int cur = kt & 1;
    __syncthreads();
    if (kt + 1 < kSteps) stage(cur ^ 1, kt + 1);

    bf16x8 af[4][2], bfr[4][2];
    #pragma unroll
    for (int m = 0; m < 4; ++m)
      #pragma unroll
      for (int kk = 0; kk < 2; ++kk)
        af[m][kk] = ldsfrag(&sA[cur][0], wr + m * 16 + r16, kk * 4 + g);
    #pragma unroll
    for (int n = 0; n < 4; ++n)
      #pragma unroll
      for (int kk = 0; kk < 2; ++kk)
        bfr[n][kk] = ldsfrag(&sB[cur][0], wc + n * 16 + r16, kk * 4 + g);
    #pragma unroll
    for (int kk = 0; kk < 2; ++kk)
      #pragma unroll
      for (int m = 0; m < 4; ++m)
        #pragma unroll
        for (int n = 0; n < 4; ++n)
          acc[m][n] = mfma16(af[m][kk], bfr[n][kk], acc[m][n]);
  }

  #pragma unroll
  for (int m = 0; m < 4; ++m) {
    const int rowb = row0 + wr + m * 16 + 4 * g;
    #pragma unroll
    for (int n = 0; n < 4; ++n) {
      const int col = col0 + wc + n * 16 + r16;
      const float bv = bias[col];
      #pragma unroll
      for (int r = 0; r < 4; ++r) {
        const size_t idx = (size_t)(rowb + r) * N + col;
        float v = acc[m][n][r] + bv;
        if (MODE == 0) {
          ((bf16_t*)outv)[idx] = (bf16_t)v;
        } else if (MODE == 1) {
          ((float*)outv)[idx] = v + res[idx];
        } else {
          ((bf16_t*)outv)[idx] = (bf16_t)gelu_f(v);
        }
      }
    }
  }
}

// ---- Flash attention: QBLK=128 (8 waves), KVBLK=64, fixed-shift exp2 softmax ----
// Grid (x=bh, y=qtile): XCD = bh%8 -> all q-blocks of one (b,h) share an XCD.
// QK^T uses contiguous k-map (k=8g+j, single b128 per K-frag); PV keeps the
// split map (k=4g+j%4+16*(j/4)) required by the in-register P layout.
__global__ __launch_bounds__(512) void attn_kernel(
    const bf16_t* __restrict__ qkv, const bf16_t* __restrict__ vt,
    bf16_t* __restrict__ o) {
  __shared__ bf16_t kbuf[2][64 * 64];
  __shared__ bf16_t vbuf[2][64 * 64];
  const int bh = blockIdx.x, b = bh / HEADS, h = bh % HEADS;
  const int q0 = blockIdx.y * 128;
  const int tid = threadIdx.x, lane = tid & 63, wid = tid >> 6;
  const int g = lane >> 4, r16 = lane & 15;

  const bf16_t* qptr = qkv + (size_t)b * SEQ * QKVLD + h * 64;
  const bf16_t* kptr = qptr + DIM;
  const bf16_t* vtp  = vt + (size_t)bh * 64 * SEQ;

  // Q fragments, contiguous map: element j of half e2 is d = e2*32 + 8g + j
  bf16x8 aq[2];
  {
    const bf16_t* qr = qptr + (size_t)(q0 + wid * 16 + r16) * QKVLD;
    aq[0] = *(const bf16x8*)(qr + 8 * g);
    aq[1] = *(const bf16x8*)(qr + 32 + 8 * g);
  }

  // K b128 read offsets: rows i*16+r16, half e2 -> chunk (4*e2+g)^(row&7)
  int koff[4][2];
  // V split-map b64 offsets (PV path)
  int voff[4][2][2];
  #pragma unroll
  for (int i = 0; i < 4; ++i) {
    const int row = i * 16 + r16, s = row & 7, rp = row * 64;
    #pragma unroll
    for (int e2 = 0; e2 < 2; ++e2) {
      koff[i][e2] = rp + (((4 * e2 + g) ^ s) << 3);
      const int o0 = e2 * 32 + 4 * g, o1 = o0 + 16;
      voff[i][e2][0] = rp + ((((o0 >> 3) ^ s) << 3) | (o0 & 7));
      voff[i][e2][1] = rp + ((((o1 >> 3) ^ s) << 3) | (o1 & 7));
    }
  }

  float lacc = 0.f;
  f32x4 acco[4];
  #pragma unroll
  for (int n = 0; n < 4; ++n) acco[n] = f32x4{0.f, 0.f, 0.f, 0.f};

  const int srow = tid >> 3, sscp = (tid & 7) ^ (srow & 7);
  const bf16_t* kSrc = kptr + (size_t)srow * QKVLD + sscp * 8;
  const bf16_t* vSrc = vtp + (size_t)srow * SEQ + sscp * 8;
  auto stage = [&](int buf, int kv0) {
    gload16(kSrc + (size_t)kv0 * QKVLD, &kbuf[buf][tid * 8]);
    gload16(vSrc + kv0, &vbuf[buf][tid * 8]);
  };

  const float C2 = 0.125f * 1.4426950408889634f;

  stage(0, 0);
  for (int it = 0; it < SEQ / 64; ++it) {
    const int cur = it & 1;
    __syncthreads();
    if (it + 1 < SEQ / 64) stage(cur ^ 1, (it + 1) * 64);
    const bf16_t* kb = kbuf[cur];
    const bf16_t* vb = vbuf[cur];

    f32x4 st[4];
    __builtin_amdgcn_s_setprio(1);
    #pragma unroll
    for (int t = 0; t < 4; ++t) {
      st[t] = f32x4{0.f, 0.f, 0.f, 0.f};
      st[t] = mfma16(*(const bf16x8*)(kb + koff[t][0]), aq[0], st[t]);
      st[t] = mfma16(*(const bf16x8*)(kb + koff[t][1]), aq[1], st[t]);
    }
    __builtin_amdgcn_s_setprio(0);

    float p[4][4];
    #pragma unroll
    for (int t = 0; t < 4; ++t)
      #pragma unroll
      for (int r = 0; r < 4; ++r) {
        float e = __builtin_amdgcn_exp2f(fmaf(st[t][r], C2, -16.0f));
        p[t][r] = e;
        lacc += e;
      }

    ABFrag pa0, pa1;
    #pragma unroll
    for (int r = 0; r < 4; ++r) {
      pa0.h[0][r] = (bf16_t)p[0][r];
      pa0.h[1][r] = (bf16_t)p[1][r];
      pa1.h[0][r] = (bf16_t)p[2][r];
      pa1.h[1][r] = (bf16_t)p[3][r];
    }

    __builtin_amdgcn_s_setprio(1);
    #pragma unroll
    for (int n = 0; n < 4; ++n) {
      ABFrag bv0, bv1;
      bv0.h[0] = *(const bf16x4*)(vb + voff[n][0][0]);
      bv0.h[1] = *(const bf16x4*)(vb + voff[n][0][1]);
      acco[n] = mfma16(pa0.v, bv0.v, acco[n]);
      bv1.h[0] = *(const bf16x4*)(vb + voff[n][1][0]);
      bv1.h[1] = *(const bf16x4*)(vb + voff[n][1][1]);
      acco[n] = mfma16(pa1.v, bv1.v, acco[n]);
    }
    __builtin_amdgcn_s_setprio(0);
  }

  float lt = lacc;
  lt += __shfl_xor(lt, 16);
  lt += __shfl_xor(lt, 32);
  float linv[4];
  #pragma unroll
  for (int r = 0; r < 4; ++r) linv[r] = 1.0f / __shfl(lt, 4 * g + r);
  bf16_t* op = o + (size_t)(b * SEQ + q0 + wid * 16 + 4 * g) * DIM + h * 64;
  #pragma unroll
  for (int n = 0; n < 4; ++n)
    #pragma unroll
    for (int r = 0; r < 4; ++r)
      op[(size_t)r * DIM + n * 16 + r16] = (bf16_t)(acco[n][r] * linv[r]);
}

extern "C" void kernel_launch(void* const* d_in, const int* in_sizes, int n_in,
                              void* d_out, int out_size, void* d_ws, size_t ws_size,
                              hipStream_t stream) {
  const float* x      = (const float*)d_in[0];
  const float* ln1_g  = (const float*)d_in[1];
  const float* ln1_b  = (const float*)d_in[2];
  const float* qkv_w  = (const float*)d_in[3];
  const float* qkv_b  = (const float*)d_in[4];
  const float* proj_w = (const float*)d_in[5];
  const float* proj_b = (const float*)d_in[6];
  const float* ln2_g  = (const float*)d_in[7];
  const float* ln2_b  = (const float*)d_in[8];
  const float* fc1_w  = (const float*)d_in[9];
  const float* fc1_b  = (const float*)d_in[10];
  const float* fc2_w  = (const float*)d_in[11];
  const float* fc2_b  = (const float*)d_in[12];
  float* out = (float*)d_out;

  char* ws = (char*)d_ws;
  size_t off = 0;
  auto alloc = [&](size_t bytes) -> void* {
    void* p = ws + off;
    off += (bytes + 255) & ~(size_t)255;
    return p;
  };
  bf16_t* wqkvT  = (bf16_t*)alloc((size_t)QKVLD * DIM * 2);
  bf16_t* wprojT = (bf16_t*)alloc((size_t)DIM * DIM * 2);
  bf16_t* wfc1T  = (bf16_t*)alloc((size_t)HIDDEN * DIM * 2);
  bf16_t* wfc2T  = (bf16_t*)alloc((size_t)DIM * HIDDEN * 2);
  bf16_t* buf1   = (bf16_t*)alloc((size_t)NTOK * DIM * 2);     // h1, then obf
  bf16_t* buf2   = (bf16_t*)alloc((size_t)NTOK * HIDDEN * 2);  // qkvbf, then h3
  bf16_t* buf3   = (bf16_t*)alloc((size_t)NTOK * DIM * 2);     // vt, then h2
  float*  x1     = (float*)alloc((size_t)NTOK * DIM * 4);

  bf16_t* h1 = buf1;     bf16_t* obf = buf1;
  bf16_t* qkvbf = buf2;  bf16_t* h3 = buf2;
  bf16_t* vt = buf3;     bf16_t* h2 = buf3;
  (void)in_sizes; (void)n_in; (void)out_size; (void)ws_size;

  dim3 tb(32, 8);
  wtrans_kernel<<<dim3(QKVLD / 32, DIM / 32), tb, 0, stream>>>(qkv_w, wqkvT, DIM, QKVLD);
  wtrans_kernel<<<dim3(DIM / 32, DIM / 32), tb, 0, stream>>>(proj_w, wprojT, DIM, DIM);
  wtrans_kernel<<<dim3(HIDDEN / 32, DIM / 32), tb, 0, stream>>>(fc1_w, wfc1T, DIM, HIDDEN);
  wtrans_kernel<<<dim3(DIM / 32, HIDDEN / 32), tb, 0, stream>>>(fc2_w, wfc2T, HIDDEN, DIM);

  ln_kernel<<<NTOK / 4, 256, 0, stream>>>(x, ln1_g, ln1_b, h1);
  gemm_sb<0><<<(QKVLD / 128) * (NTOK / 128), 256, 0, stream>>>(
      h1, wqkvT, QKVLD, DIM, qkv_b, nullptr, qkvbf, QKVLD / 128);
  vtrans_kernel<<<dim3(SEQ / 64, 8 * HEADS), 256, 0, stream>>>(qkvbf, vt);
  attn_kernel<<<dim3(8 * HEADS, SEQ / 128), 512, 0, stream>>>(qkvbf, vt, obf);
  gemm_db<1><<<(DIM / 128) * (NTOK / 128), 256, 0, stream>>>(
      obf, wprojT, DIM, DIM, proj_b, x, x1, DIM / 128);
  ln_kernel<<<NTOK / 4, 256, 0, stream>>>(x1, ln2_g, ln2_b, h2);
  gemm_sb<2><<<(HIDDEN / 128) * (NTOK / 128), 256, 0, stream>>>(
      h2, wfc1T, HIDDEN, DIM, fc1_b, nullptr, h3, HIDDEN / 128);
  gemm_db<1><<<(DIM / 128) * (NTOK / 128), 256, 0, stream>>>(
      h3, wfc2T, DIM, HIDDEN, fc2_b, x1, out, DIM / 128);
}

// Round 12
// 228.099 us; speedup vs baseline: 1.1792x; 1.0341x over previous
//
#include <hip/hip_runtime.h>
#include <math.h>

#define DIM    768
#define HEADS  12
#define HIDDEN 3072
#define SEQ    1024
#define NTOK   8192
#define QKVLD  2304

typedef __bf16 bf16_t;
typedef __bf16 bf16x4 __attribute__((ext_vector_type(4)));
typedef __bf16 bf16x8 __attribute__((ext_vector_type(8)));
typedef float  f32x4  __attribute__((ext_vector_type(4)));

union ABFrag { bf16x4 h[2]; bf16x8 v; };

__device__ __forceinline__ void gload16(const void* g, void* l) {
  __builtin_amdgcn_global_load_lds(
      (const __attribute__((address_space(1))) void*)g,
      (__attribute__((address_space(3))) void*)l, 16, 0, 0);
}

__device__ __forceinline__ f32x4 mfma16(bf16x8 a, bf16x8 b, f32x4 c) {
  return __builtin_amdgcn_mfma_f32_16x16x32_bf16(a, b, c, 0, 0, 0);
}

// BK=64 GEMM frag load: [rows][64] tile (128B rows), chunk lc stored at lc^(row&7).
__device__ __forceinline__ bf16x8 ldsfrag(const bf16_t* base, int row, int lc) {
  return *(const bf16x8*)(base + row * 64 + ((lc ^ (row & 7)) << 3));
}

// tanh-form GELU: 0.5x(1+tanh(sqrt(2/pi)(x+0.044715x^3))), max err vs exact ~3e-3.
__device__ __forceinline__ float gelu_f(float v) {
  float u = v * fmaf(v * v, 0.0356774081f, 0.7978845608f);
  u = fminf(u, 15.0f);
  float t = __builtin_amdgcn_exp2f(u * 2.8853900817779268f);  // e^{2u}
  return v * t * __builtin_amdgcn_rcpf(t + 1.0f);
}

// ---------------- LayerNorm: wave-per-row, fp32 in -> bf16 out ----------------
__global__ __launch_bounds__(256) void ln_kernel(
    const float* __restrict__ x, const float* __restrict__ gw,
    const float* __restrict__ bw, bf16_t* __restrict__ out) {
  const int row = blockIdx.x * 4 + (threadIdx.x >> 6);
  const int lane = threadIdx.x & 63;
  const float* xr = x + (size_t)row * DIM;
  f32x4 v[3];
  float s = 0.f, s2 = 0.f;
  #pragma unroll
  for (int i = 0; i < 3; ++i) {
    v[i] = *(const f32x4*)(xr + lane * 4 + i * 256);
    #pragma unroll
    for (int j = 0; j < 4; ++j) { s += v[i][j]; s2 += v[i][j] * v[i][j]; }
  }
  #pragma unroll
  for (int o = 32; o > 0; o >>= 1) {
    s += __shfl_xor(s, o);
    s2 += __shfl_xor(s2, o);
  }
  const float mu  = s * (1.0f / DIM);
  const float var = s2 * (1.0f / DIM) - mu * mu;
  const float rs  = rsqrtf(var + 1e-5f);
  bf16_t* orow = out + (size_t)row * DIM;
  #pragma unroll
  for (int i = 0; i < 3; ++i) {
    const int c = lane * 4 + i * 256;
    f32x4 gv = *(const f32x4*)(gw + c);
    f32x4 bv = *(const f32x4*)(bw + c);
    bf16x4 o4;
    #pragma unroll
    for (int j = 0; j < 4; ++j)
      o4[j] = (bf16_t)((v[i][j] - mu) * rs * gv[j] + bv[j]);
    *(bf16x4*)(orow + c) = o4;
  }
}

// ------------- Weight transpose+convert: W[K][N] f32 -> Wt[N][K] bf16 -------------
__global__ __launch_bounds__(256) void wtrans_kernel(
    const float* __restrict__ W, bf16_t* __restrict__ Wt, int K, int N) {
  __shared__ float tile[32][33];
  const int tx = threadIdx.x, ty = threadIdx.y;
  const int n0 = blockIdx.x * 32, k0 = blockIdx.y * 32;
  #pragma unroll
  for (int i = 0; i < 4; ++i)
    tile[ty + i * 8][tx] = W[(size_t)(k0 + ty + i * 8) * N + n0 + tx];
  __syncthreads();
  #pragma unroll
  for (int i = 0; i < 4; ++i)
    Wt[(size_t)(n0 + ty + i * 8) * K + k0 + tx] = (bf16_t)tile[tx][ty + i * 8];
}

// ------------- V transpose per head: qkv bf16 -> Vt[bh][64][SEQ] bf16 -------------
__global__ __launch_bounds__(256) void vtrans_kernel(
    const bf16_t* __restrict__ qkv, bf16_t* __restrict__ vt) {
  __shared__ bf16_t tile[64][65];
  const int bh = blockIdx.y, b = bh / HEADS, h = bh % HEADS;
  const int n0 = blockIdx.x * 64;
  const int t = threadIdx.x;
  const int c = t & 63, rr = t >> 6;
  const bf16_t* src = qkv + (size_t)(b * SEQ + n0) * QKVLD + 2 * DIM + h * 64;
  #pragma unroll
  for (int i = 0; i < 16; ++i)
    tile[c][rr + i * 4] = src[(size_t)(rr + i * 4) * QKVLD + c];
  __syncthreads();
  bf16_t* dst = vt + (size_t)bh * 64 * SEQ + n0;
  #pragma unroll
  for (int i = 0; i < 16; ++i)
    dst[(size_t)(rr + i * 4) * SEQ + c] = tile[rr + i * 4][c];
}

// ---- Single-buffered GEMM (occupancy regime, grid >= ~1000): BM=BN=128, BK=64 ----
// 32 KB LDS -> ~5 blocks/CU; inter-block TLP hides the staging drain (m114).
template <int MODE>
__global__ __launch_bounds__(256) void gemm_sb(
    const bf16_t* __restrict__ A, const bf16_t* __restrict__ Bt,
    int N, int K,
    const float* __restrict__ bias, const float* __restrict__ res,
    void* __restrict__ outv, int gx) {
  __shared__ bf16_t sA[128 * 64];
  __shared__ bf16_t sB[128 * 64];
  const int tid = threadIdx.x;
  const int lane = tid & 63;
  const int wid = tid >> 6;
  const int g = lane >> 4, r16 = lane & 15;

  const int nwg = gridDim.x;
  const int cpx = nwg >> 3;
  const int sw = (blockIdx.x & 7) * cpx + (blockIdx.x >> 3);
  const int bx = sw % gx, by = sw / gx;
  const int row0 = by * 128, col0 = bx * 128;
  const int wr = (wid >> 1) * 64, wc = (wid & 1) * 64;

  f32x4 acc[4][4];
  #pragma unroll
  for (int m = 0; m < 4; ++m)
    #pragma unroll
    for (int n = 0; n < 4; ++n) acc[m][n] = f32x4{0.f, 0.f, 0.f, 0.f};

  const int kSteps = K >> 6;
  for (int kt = 0; kt < kSteps; ++kt) {
    __syncthreads();
    #pragma unroll
    for (int rnd = 0; rnd < 4; ++rnd) {
      const int c = rnd * 256 + tid;
      const int row = c >> 3, scp = (c & 7) ^ (row & 7);
      gload16(A + (size_t)(row0 + row) * K + (size_t)kt * 64 + scp * 8, &sA[c * 8]);
    }
    #pragma unroll
    for (int rnd = 0; rnd < 4; ++rnd) {
      const int c = rnd * 256 + tid;
      const int row = c >> 3, scp = (c & 7) ^ (row & 7);
      gload16(Bt + (size_t)(col0 + row) * K + (size_t)kt * 64 + scp * 8, &sB[c * 8]);
    }
    __syncthreads();
    bf16x8 af[4][2], bfr[4][2];
    #pragma unroll
    for (int m = 0; m < 4; ++m)
      #pragma unroll
      for (int kk = 0; kk < 2; ++kk)
        af[m][kk] = ldsfrag(sA, wr + m * 16 + r16, kk * 4 + g);
    #pragma unroll
    for (int n = 0; n < 4; ++n)
      #pragma unroll
      for (int kk = 0; kk < 2; ++kk)
        bfr[n][kk] = ldsfrag(sB, wc + n * 16 + r16, kk * 4 + g);
    #pragma unroll
    for (int kk = 0; kk < 2; ++kk)
      #pragma unroll
      for (int m = 0; m < 4; ++m)
        #pragma unroll
        for (int n = 0; n < 4; ++n)
          acc[m][n] = mfma16(af[m][kk], bfr[n][kk], acc[m][n]);
  }

  #pragma unroll
  for (int m = 0; m < 4; ++m) {
    const int rowb = row0 + wr + m * 16 + 4 * g;
    #pragma unroll
    for (int n = 0; n < 4; ++n) {
      const int col = col0 + wc + n * 16 + r16;
      const float bv = bias[col];
      #pragma unroll
      for (int r = 0; r < 4; ++r) {
        const size_t idx = (size_t)(rowb + r) * N + col;
        float v = acc[m][n][r] + bv;
        if (MODE == 0) {
          ((bf16_t*)outv)[idx] = (bf16_t)v;
        } else if (MODE == 1) {
          ((float*)outv)[idx] = v + res[idx];
        } else {
          ((bf16_t*)outv)[idx] = (bf16_t)gelu_f(v);
        }
      }
    }
  }
}

// ---- Double-buffered BK=64 GEMM (latency regime): BM=128, BN=128|64 ----
// BN=64: grid doubles (768 = 3 blocks/CU x 256, all-resident), LDS 48 KB ->
// 3 blocks/CU, 12 waves/CU TLP on top of the double-buffer pipeline.
template <int MODE, int BN>
__global__ __launch_bounds__(256) void gemm_db(
    const bf16_t* __restrict__ A, const bf16_t* __restrict__ Bt,
    int N, int K,
    const float* __restrict__ bias, const float* __restrict__ res,
    void* __restrict__ outv, int gx) {
  constexpr int WAVES_N = (BN == 128) ? 2 : 1;
  constexpr int WM = (BN == 128) ? 4 : 2;
  constexpr int WN = 4;
  __shared__ bf16_t sA[2][128 * 64];
  __shared__ bf16_t sB[2][BN * 64];
  const int tid = threadIdx.x;
  const int lane = tid & 63;
  const int wid = tid >> 6;
  const int g = lane >> 4, r16 = lane & 15;

  const int nwg = gridDim.x;
  const int cpx = nwg >> 3;
  const int sw = (blockIdx.x & 7) * cpx + (blockIdx.x >> 3);
  const int bx = sw % gx, by = sw / gx;
  const int row0 = by * 128, col0 = bx * BN;
  const int wr = (wid / WAVES_N) * (WM * 16);
  const int wc = (wid % WAVES_N) * (WN * 16);

  auto stage = [&](int p, int kt) {
    #pragma unroll
    for (int rnd = 0; rnd < 4; ++rnd) {
      const int c = rnd * 256 + tid;
      const int row = c >> 3, scp = (c & 7) ^ (row & 7);
      gload16(A + (size_t)(row0 + row) * K + (size_t)kt * 64 + scp * 8,
              &sA[p][c * 8]);
    }
    #pragma unroll
    for (int rnd = 0; rnd < BN / 32; ++rnd) {
      const int c = rnd * 256 + tid;
      const int row = c >> 3, scp = (c & 7) ^ (row & 7);
      gload16(Bt + (size_t)(col0 + row) * K + (size_t)kt * 64 + scp * 8,
              &sB[p][c * 8]);
    }
  };

  f32x4 acc[WM][WN];
  #pragma unroll
  for (int m = 0; m < WM; ++m)
    #pragma unroll
    for (int n = 0; n < WN; ++n) acc[m][n] = f32x4{0.f, 0.f, 0.f, 0.f};

  const int kSteps = K >> 6;
  stage(0, 0);
  for (int kt = 0; kt < kSteps; ++kt) {
    const int cur = kt & 1;
    __syncthreads();
    if (kt + 1 < kSteps) stage(cur ^ 1, kt + 1);

    bf16x8 af[WM][2], bfr[WN][2];
    #pragma unroll
    for (int m = 0; m < WM; ++m)
      #pragma unroll
      for (int kk = 0; kk < 2; ++kk)
        af[m][kk] = ldsfrag(&sA[cur][0], wr + m * 16 + r16, kk * 4 + g);
    #pragma unroll
    for (int n = 0; n < WN; ++n)
      #pragma unroll
      for (int kk = 0; kk < 2; ++kk)
        bfr[n][kk] = ldsfrag(&sB[cur][0], wc + n * 16 + r16, kk * 4 + g);
    #pragma unroll
    for (int kk = 0; kk < 2; ++kk)
      #pragma unroll
      for (int m = 0; m < WM; ++m)
        #pragma unroll
        for (int n = 0; n < WN; ++n)
          acc[m][n] = mfma16(af[m][kk], bfr[n][kk], acc[m][n]);
  }

  #pragma unroll
  for (int m = 0; m < WM; ++m) {
    const int rowb = row0 + wr + m * 16 + 4 * g;
    #pragma unroll
    for (int n = 0; n < WN; ++n) {
      const int col = col0 + wc + n * 16 + r16;
      const float bv = bias[col];
      #pragma unroll
      for (int r = 0; r < 4; ++r) {
        const size_t idx = (size_t)(rowb + r) * N + col;
        float v = acc[m][n][r] + bv;
        if (MODE == 0) {
          ((bf16_t*)outv)[idx] = (bf16_t)v;
        } else if (MODE == 1) {
          ((float*)outv)[idx] = v + res[idx];
        } else {
          ((bf16_t*)outv)[idx] = (bf16_t)gelu_f(v);
        }
      }
    }
  }
}

// ---- Flash attention: QBLK=128 (8 waves), KVBLK=64, fixed-shift exp2 softmax ----
// Grid (x=bh, y=qtile): XCD = bh%8 -> all q-blocks of one (b,h) share an XCD.
// QK^T uses contiguous k-map (k=8g+j, single b128 per K-frag); PV keeps the
// split map (k=4g+j%4+16*(j/4)) required by the in-register P layout.
__global__ __launch_bounds__(512) void attn_kernel(
    const bf16_t* __restrict__ qkv, const bf16_t* __restrict__ vt,
    bf16_t* __restrict__ o) {
  __shared__ bf16_t kbuf[2][64 * 64];
  __shared__ bf16_t vbuf[2][64 * 64];
  const int bh = blockIdx.x, b = bh / HEADS, h = bh % HEADS;
  const int q0 = blockIdx.y * 128;
  const int tid = threadIdx.x, lane = tid & 63, wid = tid >> 6;
  const int g = lane >> 4, r16 = lane & 15;

  const bf16_t* qptr = qkv + (size_t)b * SEQ * QKVLD + h * 64;
  const bf16_t* kptr = qptr + DIM;
  const bf16_t* vtp  = vt + (size_t)bh * 64 * SEQ;

  bf16x8 aq[2];
  {
    const bf16_t* qr = qptr + (size_t)(q0 + wid * 16 + r16) * QKVLD;
    aq[0] = *(const bf16x8*)(qr + 8 * g);
    aq[1] = *(const bf16x8*)(qr + 32 + 8 * g);
  }

  int koff[4][2];
  int voff[4][2][2];
  #pragma unroll
  for (int i = 0; i < 4; ++i) {
    const int row = i * 16 + r16, s = row & 7, rp = row * 64;
    #pragma unroll
    for (int e2 = 0; e2 < 2; ++e2) {
      koff[i][e2] = rp + (((4 * e2 + g) ^ s) << 3);
      const int o0 = e2 * 32 + 4 * g, o1 = o0 + 16;
      voff[i][e2][0] = rp + ((((o0 >> 3) ^ s) << 3) | (o0 & 7));
      voff[i][e2][1] = rp + ((((o1 >> 3) ^ s) << 3) | (o1 & 7));
    }
  }

  float lacc = 0.f;
  f32x4 acco[4];
  #pragma unroll
  for (int n = 0; n < 4; ++n) acco[n] = f32x4{0.f, 0.f, 0.f, 0.f};

  const int srow = tid >> 3, sscp = (tid & 7) ^ (srow & 7);
  const bf16_t* kSrc = kptr + (size_t)srow * QKVLD + sscp * 8;
  const bf16_t* vSrc = vtp + (size_t)srow * SEQ + sscp * 8;
  auto stage = [&](int buf, int kv0) {
    gload16(kSrc + (size_t)kv0 * QKVLD, &kbuf[buf][tid * 8]);
    gload16(vSrc + kv0, &vbuf[buf][tid * 8]);
  };

  const float C2 = 0.125f * 1.4426950408889634f;

  stage(0, 0);
  for (int it = 0; it < SEQ / 64; ++it) {
    const int cur = it & 1;
    __syncthreads();
    if (it + 1 < SEQ / 64) stage(cur ^ 1, (it + 1) * 64);
    const bf16_t* kb = kbuf[cur];
    const bf16_t* vb = vbuf[cur];

    f32x4 st[4];
    __builtin_amdgcn_s_setprio(1);
    #pragma unroll
    for (int t = 0; t < 4; ++t) {
      st[t] = f32x4{0.f, 0.f, 0.f, 0.f};
      st[t] = mfma16(*(const bf16x8*)(kb + koff[t][0]), aq[0], st[t]);
      st[t] = mfma16(*(const bf16x8*)(kb + koff[t][1]), aq[1], st[t]);
    }
    __builtin_amdgcn_s_setprio(0);

    float p[4][4];
    #pragma unroll
    for (int t = 0; t < 4; ++t)
      #pragma unroll
      for (int r = 0; r < 4; ++r) {
        float e = __builtin_amdgcn_exp2f(fmaf(st[t][r], C2, -16.0f));
        p[t][r] = e;
        lacc += e;
      }

    ABFrag pa0, pa1;
    #pragma unroll
    for (int r = 0; r < 4; ++r) {
      pa0.h[0][r] = (bf16_t)p[0][r];
      pa0.h[1][r] = (bf16_t)p[1][r];
      pa1.h[0][r] = (bf16_t)p[2][r];
      pa1.h[1][r] = (bf16_t)p[3][r];
    }

    __builtin_amdgcn_s_setprio(1);
    #pragma unroll
    for (int n = 0; n < 4; ++n) {
      ABFrag bv0, bv1;
      bv0.h[0] = *(const bf16x4*)(vb + voff[n][0][0]);
      bv0.h[1] = *(const bf16x4*)(vb + voff[n][0][1]);
      acco[n] = mfma16(pa0.v, bv0.v, acco[n]);
      bv1.h[0] = *(const bf16x4*)(vb + voff[n][1][0]);
      bv1.h[1] = *(const bf16x4*)(vb + voff[n][1][1]);
      acco[n] = mfma16(pa1.v, bv1.v, acco[n]);
    }
    __builtin_amdgcn_s_setprio(0);
  }

  float lt = lacc;
  lt += __shfl_xor(lt, 16);
  lt += __shfl_xor(lt, 32);
  float linv[4];
  #pragma unroll
  for (int r = 0; r < 4; ++r) linv[r] = 1.0f / __shfl(lt, 4 * g + r);
  bf16_t* op = o + (size_t)(b * SEQ + q0 + wid * 16 + 4 * g) * DIM + h * 64;
  #pragma unroll
  for (int n = 0; n < 4; ++n)
    #pragma unroll
    for (int r = 0; r < 4; ++r)
      op[(size_t)r * DIM + n * 16 + r16] = (bf16_t)(acco[n][r] * linv[r]);
}

extern "C" void kernel_launch(void* const* d_in, const int* in_sizes, int n_in,
                              void* d_out, int out_size, void* d_ws, size_t ws_size,
                              hipStream_t stream) {
  const float* x      = (const float*)d_in[0];
  const float* ln1_g  = (const float*)d_in[1];
  const float* ln1_b  = (const float*)d_in[2];
  const float* qkv_w  = (const float*)d_in[3];
  const float* qkv_b  = (const float*)d_in[4];
  const float* proj_w = (const float*)d_in[5];
  const float* proj_b = (const float*)d_in[6];
  const float* ln2_g  = (const float*)d_in[7];
  const float* ln2_b  = (const float*)d_in[8];
  const float* fc1_w  = (const float*)d_in[9];
  const float* fc1_b  = (const float*)d_in[10];
  const float* fc2_w  = (const float*)d_in[11];
  const float* fc2_b  = (const float*)d_in[12];
  float* out = (float*)d_out;

  char* ws = (char*)d_ws;
  size_t off = 0;
  auto alloc = [&](size_t bytes) -> void* {
    void* p = ws + off;
    off += (bytes + 255) & ~(size_t)255;
    return p;
  };
  bf16_t* wqkvT  = (bf16_t*)alloc((size_t)QKVLD * DIM * 2);
  bf16_t* wprojT = (bf16_t*)alloc((size_t)DIM * DIM * 2);
  bf16_t* wfc1T  = (bf16_t*)alloc((size_t)HIDDEN * DIM * 2);
  bf16_t* wfc2T  = (bf16_t*)alloc((size_t)DIM * HIDDEN * 2);
  bf16_t* buf1   = (bf16_t*)alloc((size_t)NTOK * DIM * 2);     // h1, then obf
  bf16_t* buf2   = (bf16_t*)alloc((size_t)NTOK * HIDDEN * 2);  // qkvbf, then h3
  bf16_t* buf3   = (bf16_t*)alloc((size_t)NTOK * DIM * 2);     // vt, then h2
  float*  x1     = (float*)alloc((size_t)NTOK * DIM * 4);

  bf16_t* h1 = buf1;     bf16_t* obf = buf1;
  bf16_t* qkvbf = buf2;  bf16_t* h3 = buf2;
  bf16_t* vt = buf3;     bf16_t* h2 = buf3;
  (void)in_sizes; (void)n_in; (void)out_size; (void)ws_size;

  dim3 tb(32, 8);
  wtrans_kernel<<<dim3(QKVLD / 32, DIM / 32), tb, 0, stream>>>(qkv_w, wqkvT, DIM, QKVLD);
  wtrans_kernel<<<dim3(DIM / 32, DIM / 32), tb, 0, stream>>>(proj_w, wprojT, DIM, DIM);
  wtrans_kernel<<<dim3(HIDDEN / 32, DIM / 32), tb, 0, stream>>>(fc1_w, wfc1T, DIM, HIDDEN);
  wtrans_kernel<<<dim3(DIM / 32, HIDDEN / 32), tb, 0, stream>>>(fc2_w, wfc2T, HIDDEN, DIM);

  ln_kernel<<<NTOK / 4, 256, 0, stream>>>(x, ln1_g, ln1_b, h1);
  gemm_sb<0><<<(QKVLD / 128) * (NTOK / 128), 256, 0, stream>>>(
      h1, wqkvT, QKVLD, DIM, qkv_b, nullptr, qkvbf, QKVLD / 128);
  vtrans_kernel<<<dim3(SEQ / 64, 8 * HEADS), 256, 0, stream>>>(qkvbf, vt);
  attn_kernel<<<dim3(8 * HEADS, SEQ / 128), 512, 0, stream>>>(qkvbf, vt, obf);
  gemm_db<1, 64><<<(DIM / 64) * (NTOK / 128), 256, 0, stream>>>(
      obf, wprojT, DIM, DIM, proj_b, x, x1, DIM / 64);
  ln_kernel<<<NTOK / 4, 256, 0, stream>>>(x1, ln2_g, ln2_b, h2);
  gemm_sb<2><<<(HIDDEN / 128) * (NTOK / 128), 256, 0, stream>>>(
      h2, wfc1T, HIDDEN, DIM, fc1_b, nullptr, h3, HIDDEN / 128);
  gemm_db<1, 64><<<(DIM / 64) * (NTOK / 128), 256, 0, stream>>>(
      h3, wfc2T, DIM, HIDDEN, fc2_b, x1, out, DIM / 64);
}